// Round 12
// baseline (346.013 us; speedup 1.0000x reference)
//
#include <hip/hip_runtime.h>
#include <math.h>

#define NEG_SLOPE 0.2f
#define LOG2E 1.4426950408889634f

typedef __attribute__((ext_vector_type(2))) _Float16 h2;
typedef __attribute__((ext_vector_type(4))) _Float16 h4;
typedef __attribute__((ext_vector_type(8))) _Float16 f16x8;
typedef __attribute__((ext_vector_type(4))) float f32x4;

typedef const __attribute__((address_space(1))) unsigned int* gu32p;
typedef __attribute__((address_space(3))) unsigned int* lu32p;

#define GLD16(g, l) __builtin_amdgcn_global_load_lds((gu32p)(g), (lu32p)(l), 16, 0, 0)

template<int CTRL>
__device__ __forceinline__ float dpp_add_f32(float x) {
    int y = __builtin_amdgcn_update_dpp(0, __float_as_int(x), CTRL, 0xF, 0xF, true);
    return x + __int_as_float(y);
}
__device__ __forceinline__ float rowsum16(float x) {
    x = dpp_add_f32<0xB1>(x);
    x = dpp_add_f32<0x4E>(x);
    x = dpp_add_f32<0x124>(x);
    x = dpp_add_f32<0x128>(x);
    return x;
}

// ---------------- CSR build ----------------

__global__ __launch_bounds__(256) void k_scan_block(const int* __restrict__ cnt,
                                                    int* __restrict__ out,
                                                    int* __restrict__ bsums, int n) {
    __shared__ int tmp[256];
    int t = threadIdx.x;
    int i = blockIdx.x * 256 + t;
    int v = (i < n) ? cnt[i] : 0;
    tmp[t] = v;
    __syncthreads();
    for (int d = 1; d < 256; d <<= 1) {
        int add = (t >= d) ? tmp[t - d] : 0;
        __syncthreads();
        tmp[t] += add;
        __syncthreads();
    }
    if (i < n) out[i] = tmp[t] - v;
    if (t == 255) bsums[blockIdx.x] = tmp[t];
}

__global__ __launch_bounds__(256) void k_scan_bsums(int* bsums, int nb) {
    __shared__ int tmp[256];
    int t = threadIdx.x;
    int v = (t < nb) ? bsums[t] : 0;
    tmp[t] = v;
    __syncthreads();
    for (int d = 1; d < 256; d <<= 1) {
        int add = (t >= d) ? tmp[t - d] : 0;
        __syncthreads();
        tmp[t] += add;
        __syncthreads();
    }
    if (t < nb) bsums[t] = tmp[t] - v;
}

__global__ __launch_bounds__(256) void k_scan_add(int* __restrict__ out,
                                                  const int* __restrict__ bsums,
                                                  int* __restrict__ cursor,
                                                  int n, int total) {
    int i = blockIdx.x * 256 + threadIdx.x;
    if (i < n) {
        int v = out[i] + bsums[blockIdx.x];
        out[i] = v;
        cursor[i] = v;
    }
    if (i == 0) out[n] = total;
}

__global__ __launch_bounds__(256) void k_scatter(const int* __restrict__ ei, int E, int Et,
                                                 int* __restrict__ cursor,
                                                 int* __restrict__ src_sorted) {
    int e = blockIdx.x * 256 + threadIdx.x;
    if (e < Et) {
        int s, d;
        if (e < E) { s = ei[e]; d = ei[E + e]; } else { s = d = e - E; }
        int pos = atomicAdd(&cursor[d], 1);
        src_sorted[pos] = s;
    }
}

// ---------------- fused prep: edge count + x cast + all weight casts ----------------

__global__ __launch_bounds__(256) void k_prep(
        const int* __restrict__ ei, int E, int Et, int* __restrict__ cnt,
        const float* __restrict__ x, _Float16* __restrict__ xb, int N, int F,
        const float* __restrict__ Wl1, const float* __restrict__ Wr1,
        const float* __restrict__ Wl2, const float* __restrict__ Wr2,
        const float* __restrict__ Wl3, const float* __restrict__ Wr3,
        _Float16* __restrict__ wtl1, _Float16* __restrict__ wtr1,
        _Float16* __restrict__ wtl2, _Float16* __restrict__ wtr2,
        _Float16* __restrict__ w3t, int gEt, int gX) {
    const int b = blockIdx.x;
    if (b < gEt) {
        int e = b * 256 + threadIdx.x;
        if (e < Et) {
            int d = (e < E) ? ei[E + e] : (e - E);
            atomicAdd(&cnt[d], 1);
        }
    } else if (b < gEt + gX) {
        int i = (b - gEt) * 256 + threadIdx.x;
        if (i < (N << 6)) {
            int n = i >> 6, k = i & 63;
            xb[i] = (_Float16)(k < F ? x[n * F + k] : 0.0f);
        }
    } else {
        int i = (b - gEt - gX) * 256 + threadIdx.x;
        if (i < 32768) {
            const float* W = (i < 16384) ? Wl1 : Wr1;
            _Float16* O = (i < 16384) ? wtl1 : wtr1;
            int loc = i & 16383;
            int n = loc >> 6, k = loc & 63;
            O[loc] = (_Float16)(k < F ? W[k * 256 + n] : 0.0f);
        } else if (i < 163840) {
            int seg = i - 32768;
            const float* W = (seg < 65536) ? Wl2 : Wr2;
            _Float16* O = (seg < 65536) ? wtl2 : wtr2;
            int loc = seg & 65535;
            int n = loc >> 8, k = loc & 255;
            O[loc] = (_Float16)W[k * 256 + n];
        } else if (i < 167936) {
            int loc = i - 163840;
            int j = loc >> 8, k = loc & 255;
            float v = (j < 6) ? Wl3[k * 6 + j] : ((j < 12) ? Wr3[k * 6 + (j - 6)] : 0.0f);
            w3t[loc] = (_Float16)v;
        }
    }
}

// ---------------- MFMA fp16 GEMM pair — async-LDS, double-buffered ----------------
// One barrier per k-step: barrier (drains previous stage) -> async-stage NEXT buffer
// -> ds_read+MFMA current buffer. Stage for step s+1 is in flight during step s's
// compute, hiding most of the global latency.

__global__ __launch_bounds__(256) void k_gemm_pair_mfma(
        const _Float16* __restrict__ A, int M, int Kp,
        const _Float16* __restrict__ Btl, const _Float16* __restrict__ Btr,
        const float* __restrict__ bl, const float* __restrict__ br,
        _Float16* __restrict__ Cl, _Float16* __restrict__ Cr) {
    __shared__ _Float16 As[2][128 * 32];
    __shared__ _Float16 Bs[2][128 * 32];
    const int wv = threadIdx.x >> 6, lane = threadIdx.x & 63;
    const int wr = wv >> 1, wc = wv & 1;
    const int l15 = lane & 15, l4 = lane >> 4;
    const int row0 = blockIdx.x * 128;
    const int mat  = blockIdx.y >> 1;
    const int col0 = (blockIdx.y & 1) * 128;
    const _Float16* Bt = mat ? Btr : Btl;
    const float* bias  = mat ? br  : bl;
    _Float16* C        = mat ? Cr  : Cl;

    const int rl = lane >> 2;
    const int kq = (lane & 3) * 8;
    const _Float16* ga0 = A + (size_t)min(row0 + wv * 32 + rl,      M - 1) * Kp + kq;
    const _Float16* ga1 = A + (size_t)min(row0 + wv * 32 + 16 + rl, M - 1) * Kp + kq;
    const _Float16* gb0 = Bt + (size_t)(col0 + wv * 32 + rl) * Kp + kq;
    const _Float16* gb1 = Bt + (size_t)(col0 + wv * 32 + 16 + rl) * Kp + kq;

    f32x4 acc[4][4];
    #pragma unroll
    for (int a = 0; a < 4; a++)
        #pragma unroll
        for (int b = 0; b < 4; b++)
            acc[a][b] = (f32x4){0.f, 0.f, 0.f, 0.f};

    auto stage = [&](int k0, int b) {
        GLD16(ga0 + k0, &As[b][(wv * 32) * 32]);
        GLD16(ga1 + k0, &As[b][(wv * 32 + 16) * 32]);
        GLD16(gb0 + k0, &Bs[b][(wv * 32) * 32]);
        GLD16(gb1 + k0, &Bs[b][(wv * 32 + 16) * 32]);
    };

    const int nsteps = Kp >> 5;
    stage(0, 0);
    for (int s = 0; s < nsteps; s++) {
        __syncthreads();                        // drains stage of buffer s&1
        if (s + 1 < nsteps) stage((s + 1) * 32, (s + 1) & 1);
        const int b = s & 1;
        f16x8 wf[4], xf[4];
        #pragma unroll
        for (int ct = 0; ct < 4; ct++)
            wf[ct] = *(const f16x8*)&Bs[b][(wc * 64 + ct * 16 + l15) * 32 + l4 * 8];
        #pragma unroll
        for (int nt = 0; nt < 4; nt++)
            xf[nt] = *(const f16x8*)&As[b][(wr * 64 + nt * 16 + l15) * 32 + l4 * 8];
        #pragma unroll
        for (int ct = 0; ct < 4; ct++)
            #pragma unroll
            for (int nt = 0; nt < 4; nt++)
                acc[ct][nt] = __builtin_amdgcn_mfma_f32_16x16x32_f16(
                    wf[ct], xf[nt], acc[ct][nt], 0, 0, 0);
    }

    float4 bv[4];
    #pragma unroll
    for (int ct = 0; ct < 4; ct++)
        bv[ct] = *(const float4*)&bias[col0 + wc * 64 + ct * 16 + l4 * 4];
    #pragma unroll
    for (int nt = 0; nt < 4; nt++) {
        int node = row0 + wr * 64 + nt * 16 + l15;
        if (node < M) {
            #pragma unroll
            for (int ct = 0; ct < 4; ct++) {
                h4 hv = {(_Float16)(acc[ct][nt][0] + bv[ct].x),
                         (_Float16)(acc[ct][nt][1] + bv[ct].y),
                         (_Float16)(acc[ct][nt][2] + bv[ct].z),
                         (_Float16)(acc[ct][nt][3] + bv[ct].w)};
                *(h4*)&C[(size_t)node * 256 + col0 + wc * 64 + ct * 16 + l4 * 4] = hv;
            }
        }
    }
}

// ---------------- Layer 3 transform via MFMA ----------------

__global__ __launch_bounds__(256) void k_gemm3_mfma(
        const _Float16* __restrict__ h,
        const _Float16* __restrict__ W3t,
        const float* __restrict__ bl, const float* __restrict__ br,
        _Float16* __restrict__ l3, int N) {
    const int wave = threadIdx.x >> 6, lane = threadIdx.x & 63;
    const int l15 = lane & 15, l4 = lane >> 4;
    const int row0 = blockIdx.x * 64 + wave * 16;
    if (row0 >= N) return;

    f16x8 bfr[8];
    #pragma unroll
    for (int ks = 0; ks < 8; ks++)
        bfr[ks] = *(const f16x8*)&W3t[l15 * 256 + ks * 32 + l4 * 8];

    const int arow = min(row0 + l15, N - 1);
    const size_t abase = (size_t)arow * 256;
    f32x4 acc = (f32x4){0.f, 0.f, 0.f, 0.f};
    #pragma unroll
    for (int ks = 0; ks < 8; ks++) {
        f16x8 af = *(const f16x8*)&h[abase + ks * 32 + l4 * 8];
        acc = __builtin_amdgcn_mfma_f32_16x16x32_f16(af, bfr[ks], acc, 0, 0, 0);
    }
    const float bv = (l15 < 6) ? bl[l15] : ((l15 < 12) ? br[l15 - 6] : 0.0f);
    #pragma unroll
    for (int r = 0; r < 4; r++) {
        int gr = row0 + l4 * 4 + r;
        if (gr < N && l15 < 12)
            l3[(size_t)gr * 16 + l15] = (_Float16)(acc[r] + bv);
    }
}

// ---------------- Aggregation layers 1&2 (H=4, C=64), fp16, online softmax ----------------
// Ping-pong prefetch (no register copies), serial tail for <=7 remainder.

__global__ __launch_bounds__(256) void k_agg256(const _Float16* __restrict__ xl,
                                                const _Float16* __restrict__ xr,
                                                const int* __restrict__ row_ptr,
                                                const int* __restrict__ src_sorted,
                                                const float* __restrict__ att,
                                                const float* __restrict__ bias,
                                                _Float16* __restrict__ h_out, int N) {
    const int wave = threadIdx.x >> 6;
    const int lane = threadIdx.x & 63;
    const int n = __builtin_amdgcn_readfirstlane(blockIdx.x * 4 + wave);
    if (n >= N) return;
    const int ci = lane * 4;
    const h4 xr4 = *(const h4*)&xr[(size_t)n * 256 + ci];
    const float4 at4 = *(const float4*)&att[ci];
    const h2 ata = {(_Float16)(at4.x * LOG2E), (_Float16)(at4.y * LOG2E)};
    const h2 atb = {(_Float16)(at4.z * LOG2E), (_Float16)(at4.w * LOG2E)};
    float a0 = 0.f, a1 = 0.f, a2 = 0.f, a3 = 0.f;
    float m = -INFINITY, s = 0.0f;
    const int beg = row_ptr[n], end = row_ptr[n + 1];

    h4 va[8], vb[8];
    auto load8 = [&](h4 (&v)[8], int jj) {
        #pragma unroll
        for (int e = 0; e < 8; e++) {
            int sv = src_sorted[jj + e];              // uniform -> s_load
            v[e] = *(const h4*)&xl[(size_t)sv * 256 + ci];
        }
    };
    auto proc8 = [&](const h4 (&v)[8]) {
        float lg[8];
        #pragma unroll
        for (int e = 0; e < 8; e++) {
            h4 t = v[e] + xr4;
            h4 lk = __builtin_elementwise_max(t, t * (_Float16)NEG_SLOPE);
            h2 lo = __builtin_shufflevector(lk, lk, 0, 1);
            h2 hi = __builtin_shufflevector(lk, lk, 2, 3);
            lg[e] = __builtin_amdgcn_fdot2(lo, ata,
                        __builtin_amdgcn_fdot2(hi, atb, 0.0f, false), false);
        }
        #pragma unroll
        for (int e = 0; e < 8; e++) lg[e] = rowsum16(lg[e]);
        float bm = fmaxf(fmaxf(fmaxf(lg[0], lg[1]), fmaxf(lg[2], lg[3])),
                         fmaxf(fmaxf(lg[4], lg[5]), fmaxf(lg[6], lg[7])));
        float nm = fmaxf(m, bm);
        float sc = __builtin_amdgcn_exp2f(m - nm);
        a0 *= sc; a1 *= sc; a2 *= sc; a3 *= sc;
        float ps = 0.f;
        #pragma unroll
        for (int e = 0; e < 8; e++) {
            float p = __builtin_amdgcn_exp2f(lg[e] - nm);
            ps += p;
            a0 = fmaf(p, (float)v[e].x, a0);
            a1 = fmaf(p, (float)v[e].y, a1);
            a2 = fmaf(p, (float)v[e].z, a2);
            a3 = fmaf(p, (float)v[e].w, a3);
        }
        s = s * sc + ps;
        m = nm;
    };

    int j = beg;
    bool hasA = (j + 8 <= end);
    if (hasA) load8(va, j);
    while (hasA) {
        const int j1 = j + 8;
        const bool hasB = (j1 + 8 <= end);
        if (hasB) load8(vb, j1);
        proc8(va);
        if (!hasB) { j = j1; break; }
        const int j2 = j1 + 8;
        hasA = (j2 + 8 <= end);
        if (hasA) load8(va, j2);
        proc8(vb);
        j = j2;
    }
    // serial tail (<=7 edges)
    for (; j < end; j++) {
        int sv = src_sorted[j];
        h4 vv = *(const h4*)&xl[(size_t)sv * 256 + ci];
        h4 t = vv + xr4;
        h4 lk = __builtin_elementwise_max(t, t * (_Float16)NEG_SLOPE);
        h2 lo = __builtin_shufflevector(lk, lk, 0, 1);
        h2 hi = __builtin_shufflevector(lk, lk, 2, 3);
        float lg = __builtin_amdgcn_fdot2(lo, ata,
                       __builtin_amdgcn_fdot2(hi, atb, 0.0f, false), false);
        lg = rowsum16(lg);
        float nm = fmaxf(m, lg);
        float sc = __builtin_amdgcn_exp2f(m - nm);
        float p  = __builtin_amdgcn_exp2f(lg - nm);
        a0 = fmaf(p, (float)vv.x, a0 * sc);
        a1 = fmaf(p, (float)vv.y, a1 * sc);
        a2 = fmaf(p, (float)vv.z, a2 * sc);
        a3 = fmaf(p, (float)vv.w, a3 * sc);
        s = s * sc + p;
        m = nm;
    }
    const float inv = 1.0f / s;
    const float4 bv = *(const float4*)&bias[ci];
    float o0 = a0 * inv + bv.x;
    float o1 = a1 * inv + bv.y;
    float o2 = a2 * inv + bv.z;
    float o3 = a3 * inv + bv.w;
    o0 = o0 > 0.f ? o0 : (__expf(o0) - 1.f);
    o1 = o1 > 0.f ? o1 : (__expf(o1) - 1.f);
    o2 = o2 > 0.f ? o2 : (__expf(o2) - 1.f);
    o3 = o3 > 0.f ? o3 : (__expf(o3) - 1.f);
    h4 hv = {(_Float16)o0, (_Float16)o1, (_Float16)o2, (_Float16)o3};
    *(h4*)&h_out[(size_t)n * 256 + ci] = hv;
}

// ---------------- Layer 3 aggregation (H=6, C=1, mean over heads) ----------------

__global__ __launch_bounds__(64) void k_agg3(const _Float16* __restrict__ l3,
                                             const int* __restrict__ row_ptr,
                                             const int* __restrict__ src_sorted,
                                             const float* __restrict__ att3,
                                             const float* __restrict__ bias3,
                                             float* __restrict__ out, int N) {
    int n = blockIdx.x * 64 + threadIdx.x;
    if (n >= N) return;
    const h4* pn = (const h4*)&l3[(size_t)n * 16];
    h4 q1 = pn[1], q2 = pn[2];
    float xrv[6];
    xrv[0] = (float)q1.z; xrv[1] = (float)q1.w;
    xrv[2] = (float)q2.x; xrv[3] = (float)q2.y;
    xrv[4] = (float)q2.z; xrv[5] = (float)q2.w;
    float attv[6], m[6], s[6], acc[6];
    #pragma unroll
    for (int k = 0; k < 6; k++) {
        attv[k] = att3[k] * LOG2E;
        m[k] = -INFINITY; s[k] = 0.0f; acc[k] = 0.0f;
    }
    int beg = row_ptr[n], end = row_ptr[n + 1];
    for (int idx = beg; idx < end; idx++) {
        int sv = src_sorted[idx];
        const h4* ps = (const h4*)&l3[(size_t)sv * 16];
        h4 u0 = ps[0], u1 = ps[1];
        float xlv[6];
        xlv[0] = (float)u0.x; xlv[1] = (float)u0.y;
        xlv[2] = (float)u0.z; xlv[3] = (float)u0.w;
        xlv[4] = (float)u1.x; xlv[5] = (float)u1.y;
        #pragma unroll
        for (int k = 0; k < 6; k++) {
            float tt = xlv[k] + xrv[k];
            float lr = fmaxf(tt, NEG_SLOPE * tt);
            float logit = attv[k] * lr;
            float nm = fmaxf(m[k], logit);
            float sc = __builtin_amdgcn_exp2f(m[k] - nm);
            float p  = __builtin_amdgcn_exp2f(logit - nm);
            acc[k] = acc[k] * sc + p * xlv[k];
            s[k]   = s[k] * sc + p;
            m[k]   = nm;
        }
    }
    float o = 0.0f;
    #pragma unroll
    for (int k = 0; k < 6; k++) o += acc[k] / s[k];
    out[n] = o * (1.0f / 6.0f) + bias3[0];
}

// ---------------- launch ----------------

extern "C" void kernel_launch(void* const* d_in, const int* in_sizes, int n_in,
                              void* d_out, int out_size, void* d_ws, size_t ws_size,
                              hipStream_t stream) {
    const float* x    = (const float*)d_in[0];
    const int*   ei   = (const int*)  d_in[1];
    const float* Wl1  = (const float*)d_in[2];
    const float* bl1  = (const float*)d_in[3];
    const float* Wr1  = (const float*)d_in[4];
    const float* br1  = (const float*)d_in[5];
    const float* att1 = (const float*)d_in[6];
    const float* bias1= (const float*)d_in[7];
    const float* Wl2  = (const float*)d_in[8];
    const float* bl2  = (const float*)d_in[9];
    const float* Wr2  = (const float*)d_in[10];
    const float* br2  = (const float*)d_in[11];
    const float* att2 = (const float*)d_in[12];
    const float* bias2= (const float*)d_in[13];
    const float* Wl3  = (const float*)d_in[14];
    const float* bl3  = (const float*)d_in[15];
    const float* Wr3  = (const float*)d_in[16];
    const float* br3  = (const float*)d_in[17];
    const float* att3 = (const float*)d_in[18];
    const float* bias3= (const float*)d_in[19];

    const int F  = in_sizes[2] / 256;   // 58
    const int N  = in_sizes[0] / F;     // 50000
    const int E  = in_sizes[1] / 2;     // 500000
    const int Et = E + N;

    char* ws = (char*)d_ws;
    size_t off = 0;
    auto carve = [&](size_t bytes) -> char* {
        char* p = ws + off;
        off = (off + bytes + 255) & ~(size_t)255;
        return p;
    };
    _Float16* xb   = (_Float16*)carve((size_t)N * 64 * 2);
    _Float16* xlb  = (_Float16*)carve((size_t)N * 256 * 2);
    _Float16* xrb  = (_Float16*)carve((size_t)N * 256 * 2);
    _Float16* hb   = (_Float16*)carve((size_t)N * 256 * 2);
    _Float16* wtl1 = (_Float16*)carve(256 * 64 * 2);
    _Float16* wtr1 = (_Float16*)carve(256 * 64 * 2);
    _Float16* wtl2 = (_Float16*)carve(256 * 256 * 2);
    _Float16* wtr2 = (_Float16*)carve(256 * 256 * 2);
    _Float16* w3t  = (_Float16*)carve(16 * 256 * 2);
    _Float16* l3   = (_Float16*)carve((size_t)N * 16 * 2);
    int* cnt        = (int*)carve((size_t)N * 4);
    int* row_ptr    = (int*)carve((size_t)(N + 1) * 4);
    int* cursor     = (int*)carve((size_t)N * 4);
    int* src_sorted = (int*)carve((size_t)Et * 4);
    int* bsums      = (int*)carve(1024 * 4);

    const int gN  = (N + 255) / 256;
    const int gEt = (Et + 255) / 256;
    const int gX  = ((N << 6) + 255) / 256;
    const int gW  = (N + 3) / 4;

    // --- fused prep (count + casts) after zeroing cnt ---
    hipMemsetAsync(cnt, 0, (size_t)N * 4, stream);
    k_prep<<<gEt + gX + 656, 256, 0, stream>>>(ei, E, Et, cnt, x, xb, N, F,
                                               Wl1, Wr1, Wl2, Wr2, Wl3, Wr3,
                                               wtl1, wtr1, wtl2, wtr2, w3t, gEt, gX);

    // --- CSR scan + scatter ---
    k_scan_block<<<gN, 256, 0, stream>>>(cnt, row_ptr, bsums, N);
    k_scan_bsums<<<1, 256, 0, stream>>>(bsums, gN);
    k_scan_add<<<gN, 256, 0, stream>>>(row_ptr, bsums, cursor, N, Et);
    k_scatter<<<gEt, 256, 0, stream>>>(ei, E, Et, cursor, src_sorted);

    dim3 gemm_grid((N + 127) / 128, 4);

    // --- Layer 1 ---
    k_gemm_pair_mfma<<<gemm_grid, 256, 0, stream>>>(xb, N, 64, wtl1, wtr1, bl1, br1, xlb, xrb);
    k_agg256<<<gW, 256, 0, stream>>>(xlb, xrb, row_ptr, src_sorted, att1, bias1, hb, N);

    // --- Layer 2 ---
    k_gemm_pair_mfma<<<gemm_grid, 256, 0, stream>>>(hb, N, 256, wtl2, wtr2, bl2, br2, xlb, xrb);
    k_agg256<<<gW, 256, 0, stream>>>(xlb, xrb, row_ptr, src_sorted, att2, bias2, hb, N);

    // --- Layer 3 ---
    k_gemm3_mfma<<<(N + 63) / 64, 256, 0, stream>>>(hb, w3t, bl3, br3, l3, N);
    k_agg3<<<(N + 63) / 64, 64, 0, stream>>>(l3, row_ptr, src_sorted, att3, bias3,
                                             (float*)d_out, N);
}

// Round 13
// 332.163 us; speedup vs baseline: 1.0417x; 1.0417x over previous
//
#include <hip/hip_runtime.h>
#include <math.h>

#define NEG_SLOPE 0.2f
#define LOG2E 1.4426950408889634f

typedef __attribute__((ext_vector_type(2))) _Float16 h2;
typedef __attribute__((ext_vector_type(4))) _Float16 h4;
typedef __attribute__((ext_vector_type(8))) _Float16 f16x8;
typedef __attribute__((ext_vector_type(4))) float f32x4;

typedef const __attribute__((address_space(1))) unsigned int* gu32p;
typedef __attribute__((address_space(3))) unsigned int* lu32p;

#define GLD16(g, l) __builtin_amdgcn_global_load_lds((gu32p)(g), (lu32p)(l), 16, 0, 0)

template<int CTRL>
__device__ __forceinline__ float dpp_add_f32(float x) {
    int y = __builtin_amdgcn_update_dpp(0, __float_as_int(x), CTRL, 0xF, 0xF, true);
    return x + __int_as_float(y);
}
__device__ __forceinline__ float rowsum16(float x) {
    x = dpp_add_f32<0xB1>(x);
    x = dpp_add_f32<0x4E>(x);
    x = dpp_add_f32<0x124>(x);
    x = dpp_add_f32<0x128>(x);
    return x;
}

// ---------------- CSR build ----------------

__global__ __launch_bounds__(256) void k_scan_block(const int* __restrict__ cnt,
                                                    int* __restrict__ out,
                                                    int* __restrict__ bsums, int n) {
    __shared__ int tmp[256];
    int t = threadIdx.x;
    int i = blockIdx.x * 256 + t;
    int v = (i < n) ? cnt[i] : 0;
    tmp[t] = v;
    __syncthreads();
    for (int d = 1; d < 256; d <<= 1) {
        int add = (t >= d) ? tmp[t - d] : 0;
        __syncthreads();
        tmp[t] += add;
        __syncthreads();
    }
    if (i < n) out[i] = tmp[t] - v;
    if (t == 255) bsums[blockIdx.x] = tmp[t];
}

__global__ __launch_bounds__(256) void k_scan_bsums(int* bsums, int nb) {
    __shared__ int tmp[256];
    int t = threadIdx.x;
    int v = (t < nb) ? bsums[t] : 0;
    tmp[t] = v;
    __syncthreads();
    for (int d = 1; d < 256; d <<= 1) {
        int add = (t >= d) ? tmp[t - d] : 0;
        __syncthreads();
        tmp[t] += add;
        __syncthreads();
    }
    if (t < nb) bsums[t] = tmp[t] - v;
}

__global__ __launch_bounds__(256) void k_scan_add(int* __restrict__ out,
                                                  const int* __restrict__ bsums,
                                                  int* __restrict__ cursor,
                                                  int n, int total) {
    int i = blockIdx.x * 256 + threadIdx.x;
    if (i < n) {
        int v = out[i] + bsums[blockIdx.x];
        out[i] = v;
        cursor[i] = v;
    }
    if (i == 0) out[n] = total;
}

__global__ __launch_bounds__(256) void k_scatter(const int* __restrict__ ei, int E, int Et,
                                                 int* __restrict__ cursor,
                                                 int* __restrict__ src_sorted) {
    int e = blockIdx.x * 256 + threadIdx.x;
    if (e < Et) {
        int s, d;
        if (e < E) { s = ei[e]; d = ei[E + e]; } else { s = d = e - E; }
        int pos = atomicAdd(&cursor[d], 1);
        src_sorted[pos] = s;
    }
}

// ---------------- fused prep: edge count + x cast + all weight casts ----------------

__global__ __launch_bounds__(256) void k_prep(
        const int* __restrict__ ei, int E, int Et, int* __restrict__ cnt,
        const float* __restrict__ x, _Float16* __restrict__ xb, int N, int F,
        const float* __restrict__ Wl1, const float* __restrict__ Wr1,
        const float* __restrict__ Wl2, const float* __restrict__ Wr2,
        const float* __restrict__ Wl3, const float* __restrict__ Wr3,
        _Float16* __restrict__ wtl1, _Float16* __restrict__ wtr1,
        _Float16* __restrict__ wtl2, _Float16* __restrict__ wtr2,
        _Float16* __restrict__ w3t, int gEt, int gX) {
    const int b = blockIdx.x;
    if (b < gEt) {
        int e = b * 256 + threadIdx.x;
        if (e < Et) {
            int d = (e < E) ? ei[E + e] : (e - E);
            atomicAdd(&cnt[d], 1);
        }
    } else if (b < gEt + gX) {
        int i = (b - gEt) * 256 + threadIdx.x;
        if (i < (N << 6)) {
            int n = i >> 6, k = i & 63;
            xb[i] = (_Float16)(k < F ? x[n * F + k] : 0.0f);
        }
    } else {
        int i = (b - gEt - gX) * 256 + threadIdx.x;
        if (i < 32768) {
            const float* W = (i < 16384) ? Wl1 : Wr1;
            _Float16* O = (i < 16384) ? wtl1 : wtr1;
            int loc = i & 16383;
            int n = loc >> 6, k = loc & 63;
            O[loc] = (_Float16)(k < F ? W[k * 256 + n] : 0.0f);
        } else if (i < 163840) {
            int seg = i - 32768;
            const float* W = (seg < 65536) ? Wl2 : Wr2;
            _Float16* O = (seg < 65536) ? wtl2 : wtr2;
            int loc = seg & 65535;
            int n = loc >> 8, k = loc & 255;
            O[loc] = (_Float16)W[k * 256 + n];
        } else if (i < 167936) {
            int loc = i - 163840;
            int j = loc >> 8, k = loc & 255;
            float v = (j < 6) ? Wl3[k * 6 + j] : ((j < 12) ? Wr3[k * 6 + (j - 6)] : 0.0f);
            w3t[loc] = (_Float16)v;
        }
    }
}

// ---------------- MFMA fp16 GEMM pair — m97-style async-LDS, single-buffered ----------------
// (R10 version: double-buffer variant measured ~6 us SLOWER — m99/m100 pattern)

__global__ __launch_bounds__(256) void k_gemm_pair_mfma(
        const _Float16* __restrict__ A, int M, int Kp,
        const _Float16* __restrict__ Btl, const _Float16* __restrict__ Btr,
        const float* __restrict__ bl, const float* __restrict__ br,
        _Float16* __restrict__ Cl, _Float16* __restrict__ Cr) {
    __shared__ _Float16 As[128 * 32];
    __shared__ _Float16 Bs[128 * 32];
    const int wv = threadIdx.x >> 6, lane = threadIdx.x & 63;
    const int wr = wv >> 1, wc = wv & 1;
    const int l15 = lane & 15, l4 = lane >> 4;
    const int row0 = blockIdx.x * 128;
    const int mat  = blockIdx.y >> 1;
    const int col0 = (blockIdx.y & 1) * 128;
    const _Float16* Bt = mat ? Btr : Btl;
    const float* bias  = mat ? br  : bl;
    _Float16* C        = mat ? Cr  : Cl;

    const int rl = lane >> 2;
    const int kq = (lane & 3) * 8;
    const _Float16* ga0 = A + (size_t)min(row0 + wv * 32 + rl,      M - 1) * Kp + kq;
    const _Float16* ga1 = A + (size_t)min(row0 + wv * 32 + 16 + rl, M - 1) * Kp + kq;
    const _Float16* gb0 = Bt + (size_t)(col0 + wv * 32 + rl) * Kp + kq;
    const _Float16* gb1 = Bt + (size_t)(col0 + wv * 32 + 16 + rl) * Kp + kq;
    _Float16* la0 = &As[(wv * 32) * 32];
    _Float16* la1 = &As[(wv * 32 + 16) * 32];
    _Float16* lb0 = &Bs[(wv * 32) * 32];
    _Float16* lb1 = &Bs[(wv * 32 + 16) * 32];

    f32x4 acc[4][4];
    #pragma unroll
    for (int a = 0; a < 4; a++)
        #pragma unroll
        for (int b = 0; b < 4; b++)
            acc[a][b] = (f32x4){0.f, 0.f, 0.f, 0.f};

    for (int k0 = 0; k0 < Kp; k0 += 32) {
        GLD16(ga0 + k0, la0);
        GLD16(ga1 + k0, la1);
        GLD16(gb0 + k0, lb0);
        GLD16(gb1 + k0, lb1);
        __syncthreads();
        f16x8 wf[4], xf[4];
        #pragma unroll
        for (int ct = 0; ct < 4; ct++)
            wf[ct] = *(const f16x8*)&Bs[(wc * 64 + ct * 16 + l15) * 32 + l4 * 8];
        #pragma unroll
        for (int nt = 0; nt < 4; nt++)
            xf[nt] = *(const f16x8*)&As[(wr * 64 + nt * 16 + l15) * 32 + l4 * 8];
        #pragma unroll
        for (int ct = 0; ct < 4; ct++)
            #pragma unroll
            for (int nt = 0; nt < 4; nt++)
                acc[ct][nt] = __builtin_amdgcn_mfma_f32_16x16x32_f16(
                    wf[ct], xf[nt], acc[ct][nt], 0, 0, 0);
        __syncthreads();
    }

    float4 bv[4];
    #pragma unroll
    for (int ct = 0; ct < 4; ct++)
        bv[ct] = *(const float4*)&bias[col0 + wc * 64 + ct * 16 + l4 * 4];
    #pragma unroll
    for (int nt = 0; nt < 4; nt++) {
        int node = row0 + wr * 64 + nt * 16 + l15;
        if (node < M) {
            #pragma unroll
            for (int ct = 0; ct < 4; ct++) {
                h4 hv = {(_Float16)(acc[ct][nt][0] + bv[ct].x),
                         (_Float16)(acc[ct][nt][1] + bv[ct].y),
                         (_Float16)(acc[ct][nt][2] + bv[ct].z),
                         (_Float16)(acc[ct][nt][3] + bv[ct].w)};
                *(h4*)&C[(size_t)node * 256 + col0 + wc * 64 + ct * 16 + l4 * 4] = hv;
            }
        }
    }
}

// ---------------- Layer 3 transform via MFMA ----------------

__global__ __launch_bounds__(256) void k_gemm3_mfma(
        const _Float16* __restrict__ h,
        const _Float16* __restrict__ W3t,
        const float* __restrict__ bl, const float* __restrict__ br,
        _Float16* __restrict__ l3, int N) {
    const int wave = threadIdx.x >> 6, lane = threadIdx.x & 63;
    const int l15 = lane & 15, l4 = lane >> 4;
    const int row0 = blockIdx.x * 64 + wave * 16;
    if (row0 >= N) return;

    f16x8 bfr[8];
    #pragma unroll
    for (int ks = 0; ks < 8; ks++)
        bfr[ks] = *(const f16x8*)&W3t[l15 * 256 + ks * 32 + l4 * 8];

    const int arow = min(row0 + l15, N - 1);
    const size_t abase = (size_t)arow * 256;
    f32x4 acc = (f32x4){0.f, 0.f, 0.f, 0.f};
    #pragma unroll
    for (int ks = 0; ks < 8; ks++) {
        f16x8 af = *(const f16x8*)&h[abase + ks * 32 + l4 * 8];
        acc = __builtin_amdgcn_mfma_f32_16x16x32_f16(af, bfr[ks], acc, 0, 0, 0);
    }
    const float bv = (l15 < 6) ? bl[l15] : ((l15 < 12) ? br[l15 - 6] : 0.0f);
    #pragma unroll
    for (int r = 0; r < 4; r++) {
        int gr = row0 + l4 * 4 + r;
        if (gr < N && l15 < 12)
            l3[(size_t)gr * 16 + l15] = (_Float16)(acc[r] + bv);
    }
}

// ---------------- Aggregation layers 1&2 (H=4, C=64), fp16, online softmax ----------------
// R10 version: single prefetch buffer + rotation copy (36 VGPR, ~52% occ), serial tail.

__global__ __launch_bounds__(256) void k_agg256(const _Float16* __restrict__ xl,
                                                const _Float16* __restrict__ xr,
                                                const int* __restrict__ row_ptr,
                                                const int* __restrict__ src_sorted,
                                                const float* __restrict__ att,
                                                const float* __restrict__ bias,
                                                _Float16* __restrict__ h_out, int N) {
    const int wave = threadIdx.x >> 6;
    const int lane = threadIdx.x & 63;
    const int n = __builtin_amdgcn_readfirstlane(blockIdx.x * 4 + wave);
    if (n >= N) return;
    const int ci = lane * 4;
    const h4 xr4 = *(const h4*)&xr[(size_t)n * 256 + ci];
    const float4 at4 = *(const float4*)&att[ci];
    const h2 ata = {(_Float16)(at4.x * LOG2E), (_Float16)(at4.y * LOG2E)};
    const h2 atb = {(_Float16)(at4.z * LOG2E), (_Float16)(at4.w * LOG2E)};
    float a0 = 0.f, a1 = 0.f, a2 = 0.f, a3 = 0.f;
    float m = -INFINITY, s = 0.0f;
    const int beg = row_ptr[n], end = row_ptr[n + 1];

    int j = beg;
    h4 v[8], vn[8];
    bool has = (j + 8 <= end);
    if (has) {
        #pragma unroll
        for (int e = 0; e < 8; e++) {
            int sv = src_sorted[j + e];               // uniform -> s_load
            v[e] = *(const h4*)&xl[(size_t)sv * 256 + ci];
        }
    }
    while (has) {
        const int jn = j + 8;
        const bool hasN = (jn + 8 <= end);
        if (hasN) {
            #pragma unroll
            for (int e = 0; e < 8; e++) {
                int sv = src_sorted[jn + e];
                vn[e] = *(const h4*)&xl[(size_t)sv * 256 + ci];
            }
        }
        float lg[8];
        #pragma unroll
        for (int e = 0; e < 8; e++) {
            h4 t = v[e] + xr4;
            h4 lk = __builtin_elementwise_max(t, t * (_Float16)NEG_SLOPE);
            h2 lo = __builtin_shufflevector(lk, lk, 0, 1);
            h2 hi = __builtin_shufflevector(lk, lk, 2, 3);
            lg[e] = __builtin_amdgcn_fdot2(lo, ata,
                        __builtin_amdgcn_fdot2(hi, atb, 0.0f, false), false);
        }
        #pragma unroll
        for (int e = 0; e < 8; e++) lg[e] = rowsum16(lg[e]);
        float bm = fmaxf(fmaxf(fmaxf(lg[0], lg[1]), fmaxf(lg[2], lg[3])),
                         fmaxf(fmaxf(lg[4], lg[5]), fmaxf(lg[6], lg[7])));
        float nm = fmaxf(m, bm);
        float sc = __builtin_amdgcn_exp2f(m - nm);
        a0 *= sc; a1 *= sc; a2 *= sc; a3 *= sc;
        float ps = 0.f;
        #pragma unroll
        for (int e = 0; e < 8; e++) {
            float p = __builtin_amdgcn_exp2f(lg[e] - nm);
            ps += p;
            a0 = fmaf(p, (float)v[e].x, a0);
            a1 = fmaf(p, (float)v[e].y, a1);
            a2 = fmaf(p, (float)v[e].z, a2);
            a3 = fmaf(p, (float)v[e].w, a3);
        }
        s = s * sc + ps;
        m = nm;
        if (hasN) {
            #pragma unroll
            for (int e = 0; e < 8; e++) v[e] = vn[e];
        }
        j = jn;
        has = hasN;
    }
    // serial tail (<=7 edges)
    for (; j < end; j++) {
        int sv = src_sorted[j];
        h4 vv = *(const h4*)&xl[(size_t)sv * 256 + ci];
        h4 t = vv + xr4;
        h4 lk = __builtin_elementwise_max(t, t * (_Float16)NEG_SLOPE);
        h2 lo = __builtin_shufflevector(lk, lk, 0, 1);
        h2 hi = __builtin_shufflevector(lk, lk, 2, 3);
        float lg = __builtin_amdgcn_fdot2(lo, ata,
                       __builtin_amdgcn_fdot2(hi, atb, 0.0f, false), false);
        lg = rowsum16(lg);
        float nm = fmaxf(m, lg);
        float sc = __builtin_amdgcn_exp2f(m - nm);
        float p  = __builtin_amdgcn_exp2f(lg - nm);
        a0 = fmaf(p, (float)vv.x, a0 * sc);
        a1 = fmaf(p, (float)vv.y, a1 * sc);
        a2 = fmaf(p, (float)vv.z, a2 * sc);
        a3 = fmaf(p, (float)vv.w, a3 * sc);
        s = s * sc + p;
        m = nm;
    }
    const float inv = 1.0f / s;
    const float4 bv = *(const float4*)&bias[ci];
    float o0 = a0 * inv + bv.x;
    float o1 = a1 * inv + bv.y;
    float o2 = a2 * inv + bv.z;
    float o3 = a3 * inv + bv.w;
    o0 = o0 > 0.f ? o0 : (__expf(o0) - 1.f);
    o1 = o1 > 0.f ? o1 : (__expf(o1) - 1.f);
    o2 = o2 > 0.f ? o2 : (__expf(o2) - 1.f);
    o3 = o3 > 0.f ? o3 : (__expf(o3) - 1.f);
    h4 hv = {(_Float16)o0, (_Float16)o1, (_Float16)o2, (_Float16)o3};
    *(h4*)&h_out[(size_t)n * 256 + ci] = hv;
}

// ---------------- Layer 3 aggregation (H=6, C=1, mean over heads) ----------------

__global__ __launch_bounds__(64) void k_agg3(const _Float16* __restrict__ l3,
                                             const int* __restrict__ row_ptr,
                                             const int* __restrict__ src_sorted,
                                             const float* __restrict__ att3,
                                             const float* __restrict__ bias3,
                                             float* __restrict__ out, int N) {
    int n = blockIdx.x * 64 + threadIdx.x;
    if (n >= N) return;
    const h4* pn = (const h4*)&l3[(size_t)n * 16];
    h4 q1 = pn[1], q2 = pn[2];
    float xrv[6];
    xrv[0] = (float)q1.z; xrv[1] = (float)q1.w;
    xrv[2] = (float)q2.x; xrv[3] = (float)q2.y;
    xrv[4] = (float)q2.z; xrv[5] = (float)q2.w;
    float attv[6], m[6], s[6], acc[6];
    #pragma unroll
    for (int k = 0; k < 6; k++) {
        attv[k] = att3[k] * LOG2E;
        m[k] = -INFINITY; s[k] = 0.0f; acc[k] = 0.0f;
    }
    int beg = row_ptr[n], end = row_ptr[n + 1];
    for (int idx = beg; idx < end; idx++) {
        int sv = src_sorted[idx];
        const h4* ps = (const h4*)&l3[(size_t)sv * 16];
        h4 u0 = ps[0], u1 = ps[1];
        float xlv[6];
        xlv[0] = (float)u0.x; xlv[1] = (float)u0.y;
        xlv[2] = (float)u0.z; xlv[3] = (float)u0.w;
        xlv[4] = (float)u1.x; xlv[5] = (float)u1.y;
        #pragma unroll
        for (int k = 0; k < 6; k++) {
            float tt = xlv[k] + xrv[k];
            float lr = fmaxf(tt, NEG_SLOPE * tt);
            float logit = attv[k] * lr;
            float nm = fmaxf(m[k], logit);
            float sc = __builtin_amdgcn_exp2f(m[k] - nm);
            float p  = __builtin_amdgcn_exp2f(logit - nm);
            acc[k] = acc[k] * sc + p * xlv[k];
            s[k]   = s[k] * sc + p;
            m[k]   = nm;
        }
    }
    float o = 0.0f;
    #pragma unroll
    for (int k = 0; k < 6; k++) o += acc[k] / s[k];
    out[n] = o * (1.0f / 6.0f) + bias3[0];
}

// ---------------- launch ----------------

extern "C" void kernel_launch(void* const* d_in, const int* in_sizes, int n_in,
                              void* d_out, int out_size, void* d_ws, size_t ws_size,
                              hipStream_t stream) {
    const float* x    = (const float*)d_in[0];
    const int*   ei   = (const int*)  d_in[1];
    const float* Wl1  = (const float*)d_in[2];
    const float* bl1  = (const float*)d_in[3];
    const float* Wr1  = (const float*)d_in[4];
    const float* br1  = (const float*)d_in[5];
    const float* att1 = (const float*)d_in[6];
    const float* bias1= (const float*)d_in[7];
    const float* Wl2  = (const float*)d_in[8];
    const float* bl2  = (const float*)d_in[9];
    const float* Wr2  = (const float*)d_in[10];
    const float* br2  = (const float*)d_in[11];
    const float* att2 = (const float*)d_in[12];
    const float* bias2= (const float*)d_in[13];
    const float* Wl3  = (const float*)d_in[14];
    const float* bl3  = (const float*)d_in[15];
    const float* Wr3  = (const float*)d_in[16];
    const float* br3  = (const float*)d_in[17];
    const float* att3 = (const float*)d_in[18];
    const float* bias3= (const float*)d_in[19];

    const int F  = in_sizes[2] / 256;   // 58
    const int N  = in_sizes[0] / F;     // 50000
    const int E  = in_sizes[1] / 2;     // 500000
    const int Et = E + N;

    char* ws = (char*)d_ws;
    size_t off = 0;
    auto carve = [&](size_t bytes) -> char* {
        char* p = ws + off;
        off = (off + bytes + 255) & ~(size_t)255;
        return p;
    };
    _Float16* xb   = (_Float16*)carve((size_t)N * 64 * 2);
    _Float16* xlb  = (_Float16*)carve((size_t)N * 256 * 2);
    _Float16* xrb  = (_Float16*)carve((size_t)N * 256 * 2);
    _Float16* hb   = (_Float16*)carve((size_t)N * 256 * 2);
    _Float16* wtl1 = (_Float16*)carve(256 * 64 * 2);
    _Float16* wtr1 = (_Float16*)carve(256 * 64 * 2);
    _Float16* wtl2 = (_Float16*)carve(256 * 256 * 2);
    _Float16* wtr2 = (_Float16*)carve(256 * 256 * 2);
    _Float16* w3t  = (_Float16*)carve(16 * 256 * 2);
    _Float16* l3   = (_Float16*)carve((size_t)N * 16 * 2);
    int* cnt        = (int*)carve((size_t)N * 4);
    int* row_ptr    = (int*)carve((size_t)(N + 1) * 4);
    int* cursor     = (int*)carve((size_t)N * 4);
    int* src_sorted = (int*)carve((size_t)Et * 4);
    int* bsums      = (int*)carve(1024 * 4);

    const int gN  = (N + 255) / 256;
    const int gEt = (Et + 255) / 256;
    const int gX  = ((N << 6) + 255) / 256;
    const int gW  = (N + 3) / 4;

    // --- fused prep (count + casts) after zeroing cnt ---
    hipMemsetAsync(cnt, 0, (size_t)N * 4, stream);
    k_prep<<<gEt + gX + 656, 256, 0, stream>>>(ei, E, Et, cnt, x, xb, N, F,
                                               Wl1, Wr1, Wl2, Wr2, Wl3, Wr3,
                                               wtl1, wtr1, wtl2, wtr2, w3t, gEt, gX);

    // --- CSR scan + scatter ---
    k_scan_block<<<gN, 256, 0, stream>>>(cnt, row_ptr, bsums, N);
    k_scan_bsums<<<1, 256, 0, stream>>>(bsums, gN);
    k_scan_add<<<gN, 256, 0, stream>>>(row_ptr, bsums, cursor, N, Et);
    k_scatter<<<gEt, 256, 0, stream>>>(ei, E, Et, cursor, src_sorted);

    dim3 gemm_grid((N + 127) / 128, 4);

    // --- Layer 1 ---
    k_gemm_pair_mfma<<<gemm_grid, 256, 0, stream>>>(xb, N, 64, wtl1, wtr1, bl1, br1, xlb, xrb);
    k_agg256<<<gW, 256, 0, stream>>>(xlb, xrb, row_ptr, src_sorted, att1, bias1, hb, N);

    // --- Layer 2 ---
    k_gemm_pair_mfma<<<gemm_grid, 256, 0, stream>>>(hb, N, 256, wtl2, wtr2, bl2, br2, xlb, xrb);
    k_agg256<<<gW, 256, 0, stream>>>(xlb, xrb, row_ptr, src_sorted, att2, bias2, hb, N);

    // --- Layer 3 ---
    k_gemm3_mfma<<<(N + 63) / 64, 256, 0, stream>>>(hb, w3t, bl3, br3, l3, N);
    k_agg3<<<(N + 63) / 64, 64, 0, stream>>>(l3, row_ptr, src_sorted, att3, bias3,
                                             (float*)d_out, N);
}